// Round 5
// baseline (246.445 us; speedup 1.0000x reference)
//
#include <hip/hip_runtime.h>
#include <hip/hip_bf16.h>
#include <math.h>

// Problem constants
#define BATCH 8
#define SEQ   2048
#define CH    512
#define ROWS  (BATCH * SEQ)   // 16384
#define INVSQ 0.044194173824159216f  // 1/sqrt(512)

// GEMM tile config: 128x128 block tile, K-step 64 as two 128x32 sub-tiles,
// MFMA 32x32x16 (16 FLOP/LDS-byte vs 8 for 16x16x32)
#define BM 128
#define TILE_ELEMS (BM * 32)   // 4096 bf16 = 8 KB (one 128x32 sub-tile)
#define TP 68                  // transpose-tile pitch (2-way conflict = free)

typedef __attribute__((ext_vector_type(8))) __bf16 bf16x8;
typedef __attribute__((ext_vector_type(16))) float f32x16;

__device__ inline unsigned short f2bf(float f) {
    unsigned u = __builtin_bit_cast(unsigned, f);
    u += 0x7fffu + ((u >> 16) & 1u);   // round-to-nearest-even
    return (unsigned short)(u >> 16);
}
__device__ inline float bf2f(unsigned short s) {
    unsigned u = ((unsigned)s) << 16;
    return __builtin_bit_cast(float, u);
}

// Persistent stager: per-lane global pointers computed ONCE, advanced by a
// constant each K-step (kills the per-iteration 64-bit row*stride mul).
// Stages a 128x64 K-slab as two 128x32 row-major sub-tiles (h=0,1).
struct Stager {
    const unsigned short* p[4];
    unsigned short* d[4];
    __device__ __forceinline__ void init(
        const unsigned short* gbase, size_t stride,
        unsigned short* lds, int wave, int lane)
    {
        int r = lane >> 2, c = (lane & 3) << 3;
#pragma unroll
        for (int h = 0; h < 2; ++h)
#pragma unroll
            for (int j = 0; j < 2; ++j) {
                int chunk = wave * 2 + j;                 // 0..7, 16 rows each
                p[h * 2 + j] = gbase + (size_t)(chunk * 16 + r) * stride + h * 32 + c;
                d[h * 2 + j] = lds + h * TILE_ELEMS + (chunk << 9);
            }
    }
    __device__ __forceinline__ void issue() {
#pragma unroll
        for (int i = 0; i < 4; ++i)
            __builtin_amdgcn_global_load_lds(
                (const __attribute__((address_space(1))) unsigned int*)p[i],
                (__attribute__((address_space(3))) unsigned int*)d[i], 16, 0, 0);
    }
    __device__ __forceinline__ void advance() {
#pragma unroll
        for (int i = 0; i < 4; ++i) p[i] += 64;
    }
};

// One K-step-64 of 32x32x16 MFMA on staged sub-tiles. acc[2][2] f32x16.
// Wave covers a 64x64 quadrant (wm, wn); mi/ni select 32x32 tiles.
__device__ __forceinline__ void compute_step(
    const unsigned short* As, const unsigned short* Bs,
    int wm, int wn, int l31, int h5, f32x16 acc[2][2])
{
#pragma unroll
    for (int hbuf = 0; hbuf < 2; ++hbuf) {
        const unsigned short* Ab = As + hbuf * TILE_ELEMS;
        const unsigned short* Bb = Bs + hbuf * TILE_ELEMS;
#pragma unroll
        for (int j = 0; j < 2; ++j) {
            bf16x8 a[2], bb[2];
#pragma unroll
            for (int mi = 0; mi < 2; ++mi)
                a[mi] = *(const bf16x8*)(Ab + (wm + mi * 32 + l31) * 32 + j * 16 + h5 * 8);
#pragma unroll
            for (int ni = 0; ni < 2; ++ni)
                bb[ni] = *(const bf16x8*)(Bb + (wn + ni * 32 + l31) * 32 + j * 16 + h5 * 8);
#pragma unroll
            for (int mi = 0; mi < 2; ++mi)
#pragma unroll
                for (int ni = 0; ni < 2; ++ni)
                    acc[mi][ni] = __builtin_amdgcn_mfma_f32_32x32x16_bf16(
                        a[mi], bb[ni], acc[mi][ni], 0, 0, 0);
        }
    }
}

// ---------------------------------------------------------------------------
// fuse_x: x fp32 [16384,512] -> out[:, :, 0:512] (fp32) AND xb (bf16).
// Also zeroes Z (blocks 0..63).
// ---------------------------------------------------------------------------
__global__ __launch_bounds__(256) void fuse_x_kernel(
    const float* __restrict__ x, unsigned short* __restrict__ xb,
    float* __restrict__ out, float* __restrict__ Z)
{
    if (blockIdx.x < 64) Z[blockIdx.x * 256 + threadIdx.x] = 0.f;
    size_t base = ((size_t)blockIdx.x * 256 + threadIdx.x) * 8;
    size_t row = base >> 9, c = base & 511;
    float4 v0 = *(const float4*)(x + base);
    float4 v1 = *(const float4*)(x + base + 4);
    float* o = out + row * 1024 + c;
    *(float4*)o = v0;
    *(float4*)(o + 4) = v1;
    alignas(16) unsigned short t[8];
    t[0] = f2bf(v0.x); t[1] = f2bf(v0.y); t[2] = f2bf(v0.z); t[3] = f2bf(v0.w);
    t[4] = f2bf(v1.x); t[5] = f2bf(v1.y); t[6] = f2bf(v1.z); t[7] = f2bf(v1.w);
    *(uint4*)(xb + base) = *(const uint4*)t;
}

// ---------------------------------------------------------------------------
// transpose_w: W fp32 [512 k][512 n] -> Wt bf16 [3][512 n][512 k]
// ---------------------------------------------------------------------------
__global__ __launch_bounds__(256) void transpose_w_kernel(
    const float* __restrict__ Wq, const float* __restrict__ Wk,
    const float* __restrict__ Wv, unsigned short* __restrict__ Wt)
{
    __shared__ unsigned short T[64 * TP];
    const int k0 = blockIdx.x * 64, n0 = blockIdx.y * 64, w = blockIdx.z;
    const float* W = (w == 0) ? Wq : (w == 1) ? Wk : Wv;
    const int tid = threadIdx.x;
#pragma unroll
    for (int i = 0; i < 2; ++i) {
        int slot = tid + i * 256;
        int kr = slot >> 3, c8 = (slot & 7) << 3;
        float4 a = *(const float4*)(W + (size_t)(k0 + kr) * CH + n0 + c8);
        float4 b = *(const float4*)(W + (size_t)(k0 + kr) * CH + n0 + c8 + 4);
        T[(c8 + 0) * TP + kr] = f2bf(a.x); T[(c8 + 1) * TP + kr] = f2bf(a.y);
        T[(c8 + 2) * TP + kr] = f2bf(a.z); T[(c8 + 3) * TP + kr] = f2bf(a.w);
        T[(c8 + 4) * TP + kr] = f2bf(b.x); T[(c8 + 5) * TP + kr] = f2bf(b.y);
        T[(c8 + 6) * TP + kr] = f2bf(b.z); T[(c8 + 7) * TP + kr] = f2bf(b.w);
    }
    __syncthreads();
#pragma unroll
    for (int i = 0; i < 2; ++i) {
        int slot = tid + i * 256;
        int nr = slot >> 3, k8 = (slot & 7) << 3;
        uint2 lo = *(const uint2*)(T + nr * TP + k8);
        uint2 hi = *(const uint2*)(T + nr * TP + k8 + 4);
        uint4 u; u.x = lo.x; u.y = lo.y; u.z = hi.x; u.w = hi.y;
        *(uint4*)(Wt + ((size_t)w * CH + n0 + nr) * CH + k0 + k8) = u;
    }
}

// ---------------------------------------------------------------------------
// transpose_v: vb bf16 [b][s][v] -> Vt bf16 [b][v][s], scaled by 1/Z[b][s].
// ---------------------------------------------------------------------------
__global__ __launch_bounds__(256) void transpose_v_kernel(
    const unsigned short* __restrict__ vb, const float* __restrict__ Z,
    unsigned short* __restrict__ Vt)
{
    __shared__ unsigned short T[64 * TP];
    const int s0 = blockIdx.x * 64, v0 = blockIdx.y * 64, b = blockIdx.z;
    const int tid = threadIdx.x;
#pragma unroll
    for (int i = 0; i < 2; ++i) {
        int slot = tid + i * 256;
        int sr = slot >> 3, c8 = (slot & 7) << 3;
        float inv = 1.0f / Z[b * SEQ + s0 + sr];
        uint4 raw = *(const uint4*)(vb + ((size_t)b * SEQ + s0 + sr) * CH + v0 + c8);
        const unsigned short* p = (const unsigned short*)&raw;
#pragma unroll
        for (int j = 0; j < 8; ++j)
            T[(c8 + j) * TP + sr] = f2bf(bf2f(p[j]) * inv);
    }
    __syncthreads();
#pragma unroll
    for (int i = 0; i < 2; ++i) {
        int slot = tid + i * 256;
        int vr = slot >> 3, s8 = (slot & 7) << 3;
        uint2 lo = *(const uint2*)(T + vr * TP + s8);
        uint2 hi = *(const uint2*)(T + vr * TP + s8 + 4);
        uint4 u; u.x = lo.x; u.y = lo.y; u.z = hi.x; u.w = hi.y;
        *(uint4*)(Vt + ((size_t)b * CH + v0 + vr) * SEQ + s0 + s8) = u;
    }
}

// ---------------------------------------------------------------------------
// qkv fused GEMM: C[wcol(M)][xrow(N)]. A = Wt [1536][512], B = xb [16384][512].
// grid (x-tiles=128, w-tiles=12). q gets INVSQ folded in.
// ---------------------------------------------------------------------------
__global__ __launch_bounds__(256) void qkv_kernel(
    const unsigned short* __restrict__ xb, const unsigned short* __restrict__ Wt,
    const float* __restrict__ bq, const float* __restrict__ bk,
    const float* __restrict__ bv, unsigned short* __restrict__ qkv)
{
    __shared__ unsigned short As[2 * TILE_ELEMS];
    __shared__ unsigned short Bs[2 * TILE_ELEMS];
    const int xrow0 = blockIdx.x * BM;
    const int wrow0 = blockIdx.y * BM;
    const int tid = threadIdx.x;
    const int lane = tid & 63, wave = tid >> 6;
    const int wm = (wave >> 1) * 64, wn = (wave & 1) * 64;
    const int l31 = lane & 31, h5 = lane >> 5;

    Stager sA, sB;
    sA.init(Wt + (size_t)wrow0 * CH, CH, As, wave, lane);
    sB.init(xb + (size_t)xrow0 * CH, CH, Bs, wave, lane);

    f32x16 acc[2][2] = {};
#pragma unroll
    for (int ks = 0; ks < CH / 64; ++ks) {
        sA.issue(); sB.issue();
        __syncthreads();
        compute_step(As, Bs, wm, wn, l31, h5, acc);
        __syncthreads();
        sA.advance(); sB.advance();
    }
    const int which = wrow0 >> 9;   // uniform per block
    const float* bias = (which == 0) ? bq : (which == 1) ? bk : bv;
    const float scale = (which == 0) ? INVSQ : 1.0f;
    unsigned short* outw = qkv + (size_t)which * ROWS * CH;
    const int colblk = wrow0 & 511;
#pragma unroll
    for (int mi = 0; mi < 2; ++mi)
#pragma unroll
        for (int rj = 0; rj < 4; ++rj) {
            int colb = colblk + wm + mi * 32 + rj * 8 + h5 * 4;
            float4 b4 = *(const float4*)(bias + colb);
#pragma unroll
            for (int ni = 0; ni < 2; ++ni) {
                int m = xrow0 + wn + ni * 32 + l31;
                alignas(8) unsigned short pk[4];
                pk[0] = f2bf((acc[mi][ni][rj * 4 + 0] + b4.x) * scale);
                pk[1] = f2bf((acc[mi][ni][rj * 4 + 1] + b4.y) * scale);
                pk[2] = f2bf((acc[mi][ni][rj * 4 + 2] + b4.z) * scale);
                pk[3] = f2bf((acc[mi][ni][rj * 4 + 3] + b4.w) * scale);
                *(uint2*)(outw + (size_t)m * CH + colb) = *(const uint2*)pk;
            }
        }
}

// ---------------------------------------------------------------------------
// logits: C[s(M)][t(N)] = k_s . q_t (q pre-scaled by INVSQ).
// E[t][s] = exp(C) if s<=t else 0, packed 4-wide in s. Z[s] via shuffle+atomic.
// Compressed 1D grid: 136 live (st<=tt) pairs x 8 batches = 1088.
// ---------------------------------------------------------------------------
__global__ __launch_bounds__(256) void logits_kernel(
    const unsigned short* __restrict__ qb, const unsigned short* __restrict__ kb,
    unsigned short* __restrict__ E, float* __restrict__ Z)
{
    __shared__ unsigned short As[2 * TILE_ELEMS];
    __shared__ unsigned short Bs[2 * TILE_ELEMS];
    const int id = blockIdx.x;
    const int b = id & 7;
    const int i = id >> 3;                         // 0..135 triangle index
    int tt = (int)((sqrtf(8.f * (float)i + 1.f) - 1.f) * 0.5f);
    int st = i - ((tt * (tt + 1)) >> 1);
    while (st < 0)  { --tt; st = i - ((tt * (tt + 1)) >> 1); }
    while (st > tt) { ++tt; st = i - ((tt * (tt + 1)) >> 1); }
    const int m0s = st * BM;   // s rows (M)
    const int n0t = tt * BM;   // t cols (N)
    const int tid = threadIdx.x;
    const int lane = tid & 63, wave = tid >> 6;
    const int wm = (wave >> 1) * 64, wn = (wave & 1) * 64;
    const int l31 = lane & 31, h5 = lane >> 5;

    Stager sA, sB;
    sA.init(kb + (size_t)b * SEQ * CH + (size_t)m0s * CH, CH, As, wave, lane);
    sB.init(qb + (size_t)b * SEQ * CH + (size_t)n0t * CH, CH, Bs, wave, lane);

    f32x16 acc[2][2] = {};
#pragma unroll
    for (int ks = 0; ks < CH / 64; ++ks) {
        sA.issue(); sB.issue();
        __syncthreads();
        compute_step(As, Bs, wm, wn, l31, h5, acc);
        __syncthreads();
        sA.advance(); sB.advance();
    }
#pragma unroll
    for (int mi = 0; mi < 2; ++mi)
#pragma unroll
        for (int rj = 0; rj < 4; ++rj) {
            int sb = m0s + wm + mi * 32 + rj * 8 + h5 * 4;
            float ev[2][4];
#pragma unroll
            for (int ni = 0; ni < 2; ++ni) {
                int t = n0t + wn + ni * 32 + l31;
#pragma unroll
                for (int ri = 0; ri < 4; ++ri)
                    ev[ni][ri] = (sb + ri <= t) ? __expf(acc[mi][ni][rj * 4 + ri]) : 0.f;
            }
#pragma unroll
            for (int ri = 0; ri < 4; ++ri) {
                float z = ev[0][ri] + ev[1][ri];
                z += __shfl_xor(z, 1);
                z += __shfl_xor(z, 2);
                z += __shfl_xor(z, 4);
                z += __shfl_xor(z, 8);
                z += __shfl_xor(z, 16);
                if (l31 == 0) atomicAdd(&Z[b * SEQ + sb + ri], z);
            }
#pragma unroll
            for (int ni = 0; ni < 2; ++ni) {
                int t = n0t + wn + ni * 32 + l31;
                alignas(8) unsigned short pk[4];
                pk[0] = f2bf(ev[ni][0]); pk[1] = f2bf(ev[ni][1]);
                pk[2] = f2bf(ev[ni][2]); pk[3] = f2bf(ev[ni][3]);
                *(uint2*)(E + ((size_t)b * SEQ + t) * SEQ + sb) = *(const uint2*)pk;
            }
        }
}

// ---------------------------------------------------------------------------
// read: C[v(M)][t(N)] = sum_s Vt[v][s] * E[t][s] (causal K-loop).
// A = Vt [b][v][s], B = E [b][t][s]. fp32 float4 -> out[:, :, 512+v].
// 1D grid 512, tt balance-swizzled.
// ---------------------------------------------------------------------------
__global__ __launch_bounds__(256) void read_kernel(
    const unsigned short* __restrict__ E, const unsigned short* __restrict__ Vt,
    float* __restrict__ out)
{
    __shared__ unsigned short As[2 * TILE_ELEMS];
    __shared__ unsigned short Bs[2 * TILE_ELEMS];
    const int id = blockIdx.x;
    const int b = id & 7;
    const int rem = id >> 3;
    const int mv = rem & 3;                  // v tile (4)
    const int r0 = rem >> 2;                 // 0..15
    const int tt = (r0 < 8) ? r0 : 23 - r0;  // pairs (r0, r0+8) -> tt sums to 15
    const int m0v = mv * BM;
    const int n0t = tt * BM;
    const int nsteps = ((tt + 1) * BM) / 64;
    const int tid = threadIdx.x;
    const int lane = tid & 63, wave = tid >> 6;
    const int wm = (wave >> 1) * 64, wn = (wave & 1) * 64;
    const int l31 = lane & 31, h5 = lane >> 5;

    Stager sA, sB;
    sA.init(Vt + (size_t)b * CH * SEQ + (size_t)m0v * SEQ, SEQ, As, wave, lane);
    sB.init(E + (size_t)b * SEQ * SEQ + (size_t)n0t * SEQ, SEQ, Bs, wave, lane);

    f32x16 acc[2][2] = {};
    for (int ks = 0; ks < nsteps; ++ks) {
        sA.issue(); sB.issue();
        __syncthreads();
        compute_step(As, Bs, wm, wn, l31, h5, acc);
        __syncthreads();
        sA.advance(); sB.advance();
    }
#pragma unroll
    for (int mi = 0; mi < 2; ++mi)
#pragma unroll
        for (int rj = 0; rj < 4; ++rj) {
            int v = 512 + m0v + wm + mi * 32 + rj * 8 + h5 * 4;
#pragma unroll
            for (int ni = 0; ni < 2; ++ni) {
                int t = n0t + wn + ni * 32 + l31;
                float4 f;
                f.x = acc[mi][ni][rj * 4 + 0]; f.y = acc[mi][ni][rj * 4 + 1];
                f.z = acc[mi][ni][rj * 4 + 2]; f.w = acc[mi][ni][rj * 4 + 3];
                *(float4*)(out + ((size_t)b * SEQ + t) * 1024 + v) = f;
            }
        }
}

extern "C" void kernel_launch(void* const* d_in, const int* in_sizes, int n_in,
                              void* d_out, int out_size, void* d_ws, size_t ws_size,
                              hipStream_t stream) {
    const float* x  = (const float*)d_in[0];
    const float* Wq = (const float*)d_in[1];
    const float* bq = (const float*)d_in[2];
    const float* Wk = (const float*)d_in[3];
    const float* bk = (const float*)d_in[4];
    const float* Wv = (const float*)d_in[5];
    const float* bv = (const float*)d_in[6];
    float* out = (float*)d_out;

    char* ws = (char*)d_ws;
    const size_t QKV_BYTES = (size_t)ROWS * CH * 2;              // 16,777,216
    const size_t E_BYTES   = (size_t)BATCH * SEQ * SEQ * 2;      // 67,108,864
    unsigned short* qkv = (unsigned short*)ws;                   // q,k,v contiguous
    unsigned short* qb = qkv;
    unsigned short* kb = (unsigned short*)(ws + QKV_BYTES);
    unsigned short* vb = (unsigned short*)(ws + 2 * QKV_BYTES);
    unsigned short* E  = (unsigned short*)(ws + 3 * QKV_BYTES);
    float* Z = (float*)(ws + 3 * QKV_BYTES + E_BYTES);
    // Aliases (lifetimes disjoint on the in-order stream):
    unsigned short* xb = E;                                       // dead before logits writes E
    unsigned short* Wt = (unsigned short*)((char*)E + QKV_BYTES); // dead before logits writes E
    unsigned short* Vt = qb;                                      // qb dead after logits

    dim3 blk(256);
    fuse_x_kernel<<<dim3(4096), blk, 0, stream>>>(x, xb, out, Z);
    transpose_w_kernel<<<dim3(8, 8, 3), blk, 0, stream>>>(Wq, Wk, Wv, Wt);
    qkv_kernel<<<dim3(128, 12), blk, 0, stream>>>(xb, Wt, bq, bk, bv, qkv);
    logits_kernel<<<dim3(1088), blk, 0, stream>>>(qb, kb, E, Z);
    transpose_v_kernel<<<dim3(32, 8, 8), blk, 0, stream>>>(vb, Z, Vt);
    read_kernel<<<dim3(512), blk, 0, stream>>>(E, Vt, out);
}